// Round 11
// baseline (1078.707 us; speedup 1.0000x reference)
//
#include <hip/hip_runtime.h>
#include <hip/hip_bf16.h>
#include <stdint.h>

#define M_DIM 8192
#define K_DIM 4096
#define N_DIM 11008
#define NKT   (K_DIM / 32)   // 128 K-tiles of 32

typedef __attribute__((ext_vector_type(8))) short bf16x8;
typedef __attribute__((ext_vector_type(16))) float f32x16;
typedef __attribute__((ext_vector_type(4))) unsigned int uint4v;

__device__ __forceinline__ unsigned short f2bf(float f) {
    __hip_bfloat16 h = __float2bfloat16(f);
    return __builtin_bit_cast(unsigned short, h);
}

__device__ __forceinline__ void gload_lds16(const unsigned short* g, unsigned short* l) {
    __builtin_amdgcn_global_load_lds(
        (const __attribute__((address_space(1))) void*)g,
        (__attribute__((address_space(3))) void*)l,
        16, 0, 0);
}

__device__ __forceinline__ unsigned lds_addr(const unsigned short* p) {
    return (unsigned)(uintptr_t)(const __attribute__((address_space(3))) unsigned short*)p;
}

#define DSRI(dst, a, OFF) asm volatile("ds_read_b128 %0, %1 offset:%2" \
    : "=v"(dst) : "v"(a), "n"(OFF) : "memory")

#define LGKM(N) do { \
    asm volatile("s_waitcnt lgkmcnt(" #N ")" ::: "memory"); \
    __builtin_amdgcn_sched_barrier(0); \
} while (0)
#define BAR() do { __builtin_amdgcn_s_barrier(); asm volatile("" ::: "memory"); } while (0)

// ---------------------------------------------------------------------------
// Kernel 1: fused column-gather + fp32->bf16 convert.
// ---------------------------------------------------------------------------
__global__ void permute_x_kernel(const float* __restrict__ x,
                                 const int* __restrict__ ci,
                                 unsigned short* __restrict__ xg) {
    int idx = blockIdx.x * 256 + threadIdx.x;
    int64_t base = (int64_t)idx * 4;
    int m = (int)(base >> 12);        // K=4096
    int k = (int)(base & 4095);
    const float* xrow = x + ((int64_t)m << 12);
    int4 c4 = *reinterpret_cast<const int4*>(ci + k);
    ushort4 o;
    o.x = f2bf(xrow[c4.x]);
    o.y = f2bf(xrow[c4.y]);
    o.z = f2bf(xrow[c4.z]);
    o.w = f2bf(xrow[c4.w]);
    *reinterpret_cast<ushort4*>(xg + base) = o;
}

// ---------------------------------------------------------------------------
// Kernel 2: int4 unpack + per-group scale + transpose to wT[N][K] bf16.
// ---------------------------------------------------------------------------
__global__ void dequant_w_kernel(const int* __restrict__ wp,
                                 const float* __restrict__ scales,
                                 unsigned short* __restrict__ wT) {
    __shared__ unsigned short tile[64][65];
    int n0 = blockIdx.x * 64;
    int k0 = blockIdx.y * 64;
    int g = k0 >> 7;
    int t = threadIdx.x;
    int col = t & 63;
    int r0 = t >> 6;
    float s = scales[(int64_t)g * N_DIM + n0 + col];
    int pr0 = k0 >> 1;
#pragma unroll
    for (int i = 0; i < 8; ++i) {
        int row = r0 + i * 4;
        int p = wp[(int64_t)(pr0 + row) * N_DIM + n0 + col];
        tile[2 * row][col]     = f2bf((float)((p & 15) - 8) * s);
        tile[2 * row + 1][col] = f2bf((float)(((p >> 4) & 15) - 8) * s);
    }
    __syncthreads();
    int nl = t >> 2;
    int kk0 = (t & 3) << 4;
    unsigned short vals[16];
#pragma unroll
    for (int j = 0; j < 16; ++j) vals[j] = tile[kk0 + j][nl];
    uint4v* dst = reinterpret_cast<uint4v*>(wT + (int64_t)(n0 + nl) * K_DIM + k0 + kk0);
    dst[0] = *reinterpret_cast<const uint4v*>(&vals[0]);
    dst[1] = *reinterpret_cast<const uint4v*>(&vals[8]);
}

// ---------------------------------------------------------------------------
// Kernel 3: bf16 GEMM — 2-blocks/CU structure (r10) + RACE FIX (this round).
//
// r10's race: with ONE barrier/tile, stage_{j+2} (writes buf (j+2)%3 ==
// (j-1)%3) is issued by a fast wave while a slow wave is still draining its
// kf1_{j-1} reads of that same buffer inside tile j-1's body (drain happens
// at the 2nd LGKM(4), AFTER the only barrier). Fix: restore the END-OF-TILE
// barrier (BAR_b). Ledger with 2 barriers: kf1_j drains before BAR_b(j);
// every stage write to buf (j-1)%3 is issued after BAR_b(j-1) -> no wave
// writes a region any wave still reads. Outstanding-at-BAR_b reads (kf0_{j+1},
// buf (j+1)%3) never alias the stage target (j+2)%3. vmcnt/LGKM unchanged:
//   stage_{j+2}(3 gloads); vmcnt(3) [drains stage_{j+1}]; BAR_a;
//   read kf1_j(4); LGKM(4) [kf0_j ready]; 4 MFMA kf0;
//   read kf0_{j+1}(4); LGKM(4) [kf1_j ready]; 4 MFMA kf1; BAR_b.
//
// Geometry (r10): block 128x256, 8 waves of 64x64 (acc 64 regs), BK=32,
// 3 bufs x 24KB = 72KB, __launch_bounds__(512,4) -> 2 blocks/CU, 16 waves.
// LDS buf: A [128r][32k] @ buf*24576B, B [256r][32k] @ +8192B.
// Bank swizzle: phys = lin ^ (16*(r0^r2) + 32*r1) (row bits 0-2, row-
// preserving); staging inverse = pure lane col-perm; kf1 (+32B) uses
// separate pre-XORed bases (bit-5 carry hazard).
// ---------------------------------------------------------------------------

__device__ __forceinline__ void mfma4(f32x16 (&acc)[2][2], const bf16x8 (&av)[2],
                                      const bf16x8 (&bv)[2]) {
    __builtin_amdgcn_s_setprio(1);
#pragma unroll
    for (int m = 0; m < 2; ++m)
#pragma unroll
        for (int n = 0; n < 2; ++n)
            acc[m][n] = __builtin_amdgcn_mfma_f32_32x32x16_bf16(
                av[m], bv[n], acc[m][n], 0, 0, 0);
    __builtin_amdgcn_s_setprio(0);
}

// 4 ds_read_b128: A mf0/1 + B nf0/1 at k-frag of the given pre-XORed bases.
template <int BUF>
__device__ __forceinline__ void read_set(bf16x8 (&a)[2], bf16x8 (&b)[2],
                                         unsigned aB, unsigned bB) {
    DSRI(a[0], aB, BUF * 24576 + 0);
    DSRI(a[1], aB, BUF * 24576 + 2048);
    DSRI(b[0], bB, BUF * 24576 + 0);
    DSRI(b[1], bB, BUF * 24576 + 2048);
}

// stage tile t into buf BS: 1 A-load (rows w*16..+15) + 2 B-loads (rows
// w*32..+31). Source col carries the swizzle's inverse lane-perm (in ptrs).
template <int BS>
__device__ __forceinline__ void stage3(const unsigned short* pA,
                                       const unsigned short* pB,
                                       int t, unsigned short* lds, int w) {
    gload_lds16(pA + t * 32, lds + BS * 12288 + w * 512);
    gload_lds16(pB + t * 32, lds + BS * 12288 + 4096 + w * 1024);
    gload_lds16(pB + 16 * K_DIM + t * 32, lds + BS * 12288 + 4096 + w * 1024 + 512);
}

// one K-tile: B=buf j%3, BN=(j+1)%3, BS=(j+2)%3. CA_/CB_ = kf0 frags of
// tile j (issued previous phase); NA_/NB_ = kf0 frags of tile j+1.
#define PH_TILE(B, BN, BS, CA_, CB_, NA_, NB_, tt)                        \
    do {                                                                  \
        stage3<BS>(pA, pB, (tt), lds, w);                                 \
        asm volatile("s_waitcnt vmcnt(3)" ::: "memory");                  \
        BAR();                                                            \
        read_set<B>(aZ, bZ, aK1, bK1);                                    \
        LGKM(4);                                                          \
        mfma4(acc, CA_, CB_);                                             \
        read_set<BN>(NA_, NB_, aK0, bK0);                                 \
        LGKM(4);                                                          \
        mfma4(acc, aZ, bZ);                                               \
        BAR();                                                            \
    } while (0)

__global__ __launch_bounds__(512, 4)
void gemm_kernel(const unsigned short* __restrict__ A,
                 const unsigned short* __restrict__ BT,
                 const float* __restrict__ bias,
                 float* __restrict__ C) {
    __shared__ unsigned short lds[36864];   // 72 KiB: 3 bufs x 24 KiB

    constexpr int NT = N_DIM / 256;  // 43 col-tiles
    int wg = blockIdx.x, nwg = gridDim.x;
    int q = nwg >> 3, r = nwg & 7;
    int xcd = wg & 7, li = wg >> 3;
    int swz = (xcd < r ? xcd * (q + 1) : r * (q + 1) + (xcd - r) * q) + li;
    int by = swz / NT, bx = swz - by * NT;
    int brow = by << 7, bcol = bx << 8;   // 128 x 256 block

    int t = threadIdx.x;
    int lane = t & 63, w = t >> 6;
    int wr = w >> 2, wc = w & 3;          // 2 x 4 wave grid, 64x64 per wave
    int l31 = lane & 31, hi = lane >> 5;

    // read-side swizzle XOR (row bits 0..2 of l31): bytes
    const unsigned xr = (unsigned)(16 * ((l31 & 1) ^ ((l31 >> 2) & 1)) +
                                   32 * ((l31 >> 1) & 1));
    // staging lane geometry + inverse col-perm (elements)
    const int riw = lane >> 2;
    const int rr = riw & 7;
    const int cperm = 8 * ((lane & 1) ^ (rr & 1) ^ ((rr >> 2) & 1)) +
                      16 * (((lane >> 1) & 1) ^ ((rr >> 1) & 1));

    const unsigned ldsB = lds_addr(lds);
    const unsigned lin_a = (unsigned)((wr * 64 + l31) * 64 + hi * 16);
    const unsigned lin_b = (unsigned)((wc * 64 + l31) * 64 + hi * 16);
    const unsigned aK0 = ldsB + (lin_a ^ xr);
    const unsigned aK1 = ldsB + ((lin_a + 32) ^ xr);
    const unsigned bK0 = ldsB + 8192u + (lin_b ^ xr);
    const unsigned bK1 = ldsB + 8192u + ((lin_b + 32) ^ xr);

    // staging source pointers (k advances via t*32)
    const unsigned short* pA = A + (int64_t)(brow + w * 16 + riw) * K_DIM + cperm;
    const unsigned short* pB = BT + (int64_t)(bcol + w * 32 + riw) * K_DIM + cperm;

    f32x16 acc[2][2];
#pragma unroll
    for (int m = 0; m < 2; ++m)
#pragma unroll
        for (int n = 0; n < 2; ++n)
#pragma unroll
            for (int j = 0; j < 16; ++j) acc[m][n][j] = 0.f;

    bf16x8 aX[2], bX[2], aY[2], bY[2], aZ[2], bZ[2];

    // ---- prologue: stage tiles 0,1 -> bufs 0,1; confirm buf0; pre-issue
    // kf0_0 (color X). Leaves stage_1 (3 loads) outstanding = induction state.
    stage3<0>(pA, pB, 0, lds, w);
    stage3<1>(pA, pB, 1, lds, w);
    asm volatile("s_waitcnt vmcnt(3)" ::: "memory");
    BAR();
    read_set<0>(aX, bX, aK0, bK0);

#pragma unroll 1
    for (int body = 0; body < 21; ++body) {
        const int t2 = body * 6 + 2;
        PH_TILE(0, 1, 2, aX, bX, aY, bY, t2);       // tile 6b+0 (X -> Y)
        PH_TILE(1, 2, 0, aY, bY, aX, bX, t2 + 1);   // tile 6b+1 (Y -> X)
        PH_TILE(2, 0, 1, aX, bX, aY, bY, t2 + 2);   // tile 6b+2
        PH_TILE(0, 1, 2, aY, bY, aX, bX, t2 + 3);   // tile 6b+3
        PH_TILE(1, 2, 0, aX, bX, aY, bY, t2 + 4);   // tile 6b+4
        PH_TILE(2, 0, 1, aY, bY, aX, bX, t2 + 5);   // tile 6b+5
    }

    // ---- tail: tile 126 (buf0, X) and 127 (buf1, Y), no stages.
    asm volatile("s_waitcnt vmcnt(0)" ::: "memory");   // drain stage_127
    BAR();
    read_set<0>(aZ, bZ, aK1, bK1);
    LGKM(4);
    mfma4(acc, aX, bX);
    read_set<1>(aY, bY, aK0, bK0);
    LGKM(4);
    mfma4(acc, aZ, bZ);
    // tile 127
    read_set<1>(aZ, bZ, aK1, bK1);
    LGKM(4);
    mfma4(acc, aY, bY);
    LGKM(0);
    mfma4(acc, aZ, bZ);

    // ---- epilogue: 32x32 C/D layout col=lane&31,
    // row = (reg&3) + 8*(reg>>2) + 4*(lane>>5) ----
    int orow0 = brow + wr * 64 + 4 * hi;
    int ocol0 = bcol + wc * 64 + l31;
#pragma unroll
    for (int n = 0; n < 2; ++n) {
        int col = ocol0 + n * 32;
        float bval = bias[col];
#pragma unroll
        for (int m = 0; m < 2; ++m) {
            int rbase = orow0 + m * 32;
#pragma unroll
            for (int j = 0; j < 16; ++j) {
                int row = rbase + (j & 3) + 8 * (j >> 2);
                C[(int64_t)row * N_DIM + col] = acc[m][n][j] + bval;
            }
        }
    }
}

extern "C" void kernel_launch(void* const* d_in, const int* in_sizes, int n_in,
                              void* d_out, int out_size, void* d_ws, size_t ws_size,
                              hipStream_t stream) {
    const float* x      = (const float*)d_in[0];
    const int* ci       = (const int*)d_in[1];
    const int* wp       = (const int*)d_in[2];
    const float* scales = (const float*)d_in[3];
    const float* bias   = (const float*)d_in[4];
    float* out          = (float*)d_out;

    const size_t wT_bytes = (size_t)N_DIM * K_DIM * 2;
    unsigned short* wT = (unsigned short*)d_ws;
    unsigned short* xg = wT + (size_t)N_DIM * K_DIM;

    size_t cap = (ws_size > wT_bytes) ? (ws_size - wT_bytes) : 0;
    int max_rows = (int)(cap / ((size_t)K_DIM * 2));
    int chunk_rows = (max_rows / 128) * 128;
    if (chunk_rows <= 0) chunk_rows = 128;      // best effort
    if (chunk_rows > M_DIM) chunk_rows = M_DIM;

    dequant_w_kernel<<<dim3(N_DIM / 64, K_DIM / 64), 256, 0, stream>>>(wp, scales, wT);

    for (int m0 = 0; m0 < M_DIM; m0 += chunk_rows) {
        int rows = M_DIM - m0 < chunk_rows ? M_DIM - m0 : chunk_rows;
        int pgrid = (int)(((int64_t)rows * K_DIM) / (4 * 256));
        permute_x_kernel<<<pgrid, 256, 0, stream>>>(
            x + (int64_t)m0 * K_DIM, ci, xg);
        int grid = (rows / 128) * (N_DIM / 256);
        gemm_kernel<<<grid, 512, 0, stream>>>(
            xg, wT, bias, out + (int64_t)m0 * N_DIM);
    }
}

// Round 12
// 877.738 us; speedup vs baseline: 1.2290x; 1.2290x over previous
//
#include <hip/hip_runtime.h>
#include <hip/hip_bf16.h>
#include <stdint.h>

#define M_DIM 8192
#define K_DIM 4096
#define N_DIM 11008

typedef __attribute__((ext_vector_type(8))) short bf16x8;
typedef __attribute__((ext_vector_type(16))) float f32x16;
typedef __attribute__((ext_vector_type(4))) unsigned int uint4v;

__device__ __forceinline__ unsigned short f2bf(float f) {
    __hip_bfloat16 h = __float2bfloat16(f);
    return __builtin_bit_cast(unsigned short, h);
}

__device__ __forceinline__ void gload_lds16(const unsigned short* g, unsigned short* l) {
    __builtin_amdgcn_global_load_lds(
        (const __attribute__((address_space(1))) void*)g,
        (__attribute__((address_space(3))) void*)l,
        16, 0, 0);
}

__device__ __forceinline__ unsigned lds_addr(const unsigned short* p) {
    return (unsigned)(uintptr_t)(const __attribute__((address_space(3))) unsigned short*)p;
}

// inline-asm ds_read_b128; hand-placed counted lgkm waits order the consumers.
#define DSRI(dst, a, OFF) asm volatile("ds_read_b128 %0, %1 offset:%2" \
    : "=v"(dst) : "v"(a), "n"(OFF) : "memory")

// counted lgkm wait + scheduler fence (rule #18).
#define LGKM(N) do { \
    asm volatile("s_waitcnt lgkmcnt(" #N ")" ::: "memory"); \
    __builtin_amdgcn_sched_barrier(0); \
} while (0)
#define BAR() do { __builtin_amdgcn_s_barrier(); asm volatile("" ::: "memory"); } while (0)

// ---------------------------------------------------------------------------
// Kernel 1: fused column-gather + fp32->bf16 convert.
// ---------------------------------------------------------------------------
__global__ void permute_x_kernel(const float* __restrict__ x,
                                 const int* __restrict__ ci,
                                 unsigned short* __restrict__ xg) {
    int idx = blockIdx.x * 256 + threadIdx.x;
    int64_t base = (int64_t)idx * 4;
    int m = (int)(base >> 12);        // K=4096
    int k = (int)(base & 4095);
    const float* xrow = x + ((int64_t)m << 12);
    int4 c4 = *reinterpret_cast<const int4*>(ci + k);
    ushort4 o;
    o.x = f2bf(xrow[c4.x]);
    o.y = f2bf(xrow[c4.y]);
    o.z = f2bf(xrow[c4.z]);
    o.w = f2bf(xrow[c4.w]);
    *reinterpret_cast<ushort4*>(xg + base) = o;
}

// ---------------------------------------------------------------------------
// Kernel 2: int4 unpack + per-group scale + transpose to wT[N][K] bf16.
// ---------------------------------------------------------------------------
__global__ void dequant_w_kernel(const int* __restrict__ wp,
                                 const float* __restrict__ scales,
                                 unsigned short* __restrict__ wT) {
    __shared__ unsigned short tile[64][65];
    int n0 = blockIdx.x * 64;
    int k0 = blockIdx.y * 64;
    int g = k0 >> 7;
    int t = threadIdx.x;
    int col = t & 63;
    int r0 = t >> 6;
    float s = scales[(int64_t)g * N_DIM + n0 + col];
    int pr0 = k0 >> 1;
#pragma unroll
    for (int i = 0; i < 8; ++i) {
        int row = r0 + i * 4;
        int p = wp[(int64_t)(pr0 + row) * N_DIM + n0 + col];
        tile[2 * row][col]     = f2bf((float)((p & 15) - 8) * s);
        tile[2 * row + 1][col] = f2bf((float)(((p >> 4) & 15) - 8) * s);
    }
    __syncthreads();
    int nl = t >> 2;
    int kk0 = (t & 3) << 4;
    unsigned short vals[16];
#pragma unroll
    for (int j = 0; j < 16; ++j) vals[j] = tile[kk0 + j][nl];
    uint4v* dst = reinterpret_cast<uint4v*>(wT + (int64_t)(n0 + nl) * K_DIM + k0 + kk0);
    dst[0] = *reinterpret_cast<const uint4v*>(&vals[0]);
    dst[1] = *reinterpret_cast<const uint4v*>(&vals[8]);
}

// ---------------------------------------------------------------------------
// Kernel 3: bf16 GEMM — REVERT to round-9 best (256x256, 3-buf BK=32,
// 32x32x16, 2 barriers/tile) + DEPTH-2 READ-AHEAD (this round's change).
//
// r11 regression lesson: 128x256 tiles doubled HBM traffic (FETCH 1.6->3.2GB)
// — tile intensity dominates occupancy. Back to 256² (1-resident).
//
// Depth-2: both read sets of tile j+1 (S(j+1,0), S(j+1,1); 6 ds_read each)
// are issued DURING tile j — a full tile (~2500 cyc) of lead instead of half
// a phase — with counted LGKM(12) (= the two newer in-flight sets).
//
// Per tile j (buf B=j%3, BN=(j+1)%3, BS=(j+2)%3):
//  P1: stage A_{j+2}; vmcnt(2) [drains A_{j+1},B_{j+1} -> buf j+1 confirmed];
//      BAR; issue S(j+1,0) [buf j+1 — AFTER the confirming barrier: no stale
//      read, the r10 lesson]; LGKM(12) [S(j,0) ready]; 4 MFMA kf0_j.
//  P2: stage B_{j+2}; issue S(j+1,1); LGKM(12) [S(j,1) ready]; 4 MFMA kf1_j;
//      BAR.
// vmcnt ledger (4 gloads/tile): at P1(j) outstanding = {A_{j+1},B_{j+1},
// A_{j+2}} = 6 -> vmcnt(2) leaves A_{j+2} only. Overwrite ledger: stage into
// buf (j+2)%3 == (j-1)%3; its last reads S(j-1,1) drained at P2(j-1)'s
// LGKM(12), >=1 barrier (P2 end-BAR) before the stage issue at P1(j). Reads
// S(j+1,*) drain at their consuming LGKM, >=2 barriers before buf (j+1)%3
// is next overwritten (stage A_{j+4} at P1(j+2)). All safe.
//
// Swizzle (r9): phys = lin ^ ((lane&6)<<3) ^ ((lane&16)<<1); kf1 (+32B)
// pre-XORed bases; staging source col perm s8 (j=0) / s8^16 (j=1 slice).
// ---------------------------------------------------------------------------

__device__ __forceinline__ void mfma_tile(f32x16 (&acc)[4][2], const bf16x8 (&av)[4],
                                          const bf16x8 (&bv)[2]) {
    __builtin_amdgcn_s_setprio(1);
#pragma unroll
    for (int m = 0; m < 4; ++m)
#pragma unroll
        for (int n = 0; n < 2; ++n)
            acc[m][n] = __builtin_amdgcn_mfma_f32_32x32x16_bf16(
                av[m], bv[n], acc[m][n], 0, 0, 0);
    __builtin_amdgcn_s_setprio(0);
}

// read one k-frag set (6 x ds_read_b128): A m0-3 + B n0-1 of buf BUF.
template <int BUF>
__device__ __forceinline__ void read_set(bf16x8 (&a)[4], bf16x8 (&b)[2],
                                         unsigned aB, unsigned aB2,
                                         unsigned bB, unsigned bB2) {
    const unsigned ad = (BUF < 2) ? aB : aB2;
    const unsigned bd = (BUF < 2) ? bB : bB2;
    constexpr int bo = (BUF < 2) ? BUF * 32768 : 0;
    DSRI(a[0], ad, bo + 0);
    DSRI(a[1], ad, bo + 2048);
    DSRI(a[2], ad, bo + 4096);
    DSRI(a[3], ad, bo + 6144);
    DSRI(b[0], bd, bo + 0);
    DSRI(b[1], bd, bo + 2048);
}

// stage one 16 KiB region (256 rows x 32 k) of K-tile t into buf DBUF.
template <int DBUF, int ISB>
__device__ __forceinline__ void stage2(const unsigned short* p0, const unsigned short* p1,
                                       int t, unsigned short* lds, int wLds) {
    const unsigned short* s0 = p0 + t * 32;
    const unsigned short* s1 = p1 + t * 32;
    unsigned short* d = lds + DBUF * 16384 + ISB * 8192 + wLds;
    gload_lds16(s0, d);
    gload_lds16(s1, d + 512);
}

// one K-tile, depth-2: consume C*(tile j), issue N*(tile j+1), stage tt=j+2.
#define PH_TILE(B, BN, BS, CA0, CB0, CA1, CB1, NA0, NB0, NA1, NB1, tt)    \
    do {                                                                  \
        stage2<BS, 0>(pA0, pA1, (tt), lds, wLds);                         \
        asm volatile("s_waitcnt vmcnt(2)" ::: "memory");                  \
        BAR();                                                            \
        read_set<BN>(NA0, NB0, aK0, aK0_2, bK0, bK0_2);                   \
        LGKM(12);                                                         \
        mfma_tile(acc, CA0, CB0);                                         \
        stage2<BS, 1>(pB0, pB1, (tt), lds, wLds);                         \
        read_set<BN>(NA1, NB1, aK1, aK1_2, bK1, bK1_2);                   \
        LGKM(12);                                                         \
        mfma_tile(acc, CA1, CB1);                                         \
        BAR();                                                            \
    } while (0)

__global__ __launch_bounds__(512, 2)
void gemm_kernel(const unsigned short* __restrict__ A,
                 const unsigned short* __restrict__ BT,
                 const float* __restrict__ bias,
                 float* __restrict__ C) {
    __shared__ unsigned short lds[49152];   // 96 KiB: 3 bufs x 32 KiB

    constexpr int NT = N_DIM / 256;  // 43
    int wg = blockIdx.x, nwg = gridDim.x;
    int q = nwg >> 3, r = nwg & 7;
    int xcd = wg & 7, li = wg >> 3;
    int swz = (xcd < r ? xcd * (q + 1) : r * (q + 1) + (xcd - r) * q) + li;
    int by = swz / NT, bx = swz - by * NT;
    int brow = by << 8, bcol = bx << 8;

    int t = threadIdx.x;
    int lane = t & 63, w = t >> 6;
    int wr = w >> 2, wc = w & 3;           // 2 x 4 wave grid
    int l31 = lane & 31, hi = lane >> 5;

    const unsigned xr = (unsigned)(((lane & 6) << 3) ^ ((lane & 16) << 1));
    const int riw = lane >> 2;
    const int s8 = ((lane & 3) ^ ((lane >> 3) & 3)) << 3;   // j=0 source perm
    const int w32 = w * 32, wLds = w * 1024;

    const unsigned ldsB = lds_addr(lds);
    const unsigned lin_a = (unsigned)((wr * 128 + l31) * 64 + hi * 16);
    const unsigned lin_b = (unsigned)((wc * 64 + l31) * 64 + hi * 16);
    const unsigned aK0 = ldsB + (lin_a ^ xr);
    const unsigned aK1 = ldsB + ((lin_a + 32) ^ xr);
    const unsigned bK0 = ldsB + 16384u + (lin_b ^ xr);
    const unsigned bK1 = ldsB + 16384u + ((lin_b + 32) ^ xr);
    const unsigned aK0_2 = aK0 + 65536, aK1_2 = aK1 + 65536;
    const unsigned bK0_2 = bK0 + 65536, bK1_2 = bK1 + 65536;

    // staging source pointers (rows 0-15 slice: perm s8; rows 16-31: s8^16).
    const unsigned short* pA0 = A + (int64_t)(brow + w32 + riw) * K_DIM + s8;
    const unsigned short* pA1 = A + (int64_t)(brow + w32 + 16 + riw) * K_DIM + (s8 ^ 16);
    const unsigned short* pB0 = BT + (int64_t)(bcol + w32 + riw) * K_DIM + s8;
    const unsigned short* pB1 = BT + (int64_t)(bcol + w32 + 16 + riw) * K_DIM + (s8 ^ 16);

    f32x16 acc[4][2];
#pragma unroll
    for (int m = 0; m < 4; ++m)
#pragma unroll
        for (int n = 0; n < 2; ++n)
#pragma unroll
            for (int j = 0; j < 16; ++j) acc[m][n][j] = 0.f;

    // depth-2 frag sets: E = even tiles, O = odd tiles; 0/1 = kf0/kf1.
    bf16x8 aE0[4], bE0[2], aE1[4], bE1[2];
    bf16x8 aO0[4], bO0[2], aO1[4], bO1[2];

    // ---- prologue: stage tiles 0,1 -> bufs 0,1; vmcnt(4) confirms buf0
    // (leaves A1,B1 outstanding = induction state); pre-issue BOTH sets of
    // tile 0 (buf0, confirmed).
    stage2<0, 0>(pA0, pA1, 0, lds, wLds);
    stage2<0, 1>(pB0, pB1, 0, lds, wLds);
    stage2<1, 0>(pA0, pA1, 1, lds, wLds);
    stage2<1, 1>(pB0, pB1, 1, lds, wLds);
    asm volatile("s_waitcnt vmcnt(4)" ::: "memory");
    BAR();
    read_set<0>(aE0, bE0, aK0, aK0_2, bK0, bK0_2);
    read_set<0>(aE1, bE1, aK1, aK1_2, bK1, bK1_2);

#pragma unroll 1
    for (int body = 0; body < 21; ++body) {
        const int t2 = body * 6 + 2;
        PH_TILE(0, 1, 2, aE0, bE0, aE1, bE1, aO0, bO0, aO1, bO1, t2);      // tile 6b+0
        PH_TILE(1, 2, 0, aO0, bO0, aO1, bO1, aE0, bE0, aE1, bE1, t2 + 1);  // tile 6b+1
        PH_TILE(2, 0, 1, aE0, bE0, aE1, bE1, aO0, bO0, aO1, bO1, t2 + 2);  // tile 6b+2
        PH_TILE(0, 1, 2, aO0, bO0, aO1, bO1, aE0, bE0, aE1, bE1, t2 + 3);  // tile 6b+3
        PH_TILE(1, 2, 0, aE0, bE0, aE1, bE1, aO0, bO0, aO1, bO1, t2 + 4);  // tile 6b+4
        PH_TILE(2, 0, 1, aO0, bO0, aO1, bO1, aE0, bE0, aE1, bE1, t2 + 5);  // tile 6b+5
    }

    // ---- tail: tile 126 (buf0, E) and 127 (buf1, O), no stages.
    asm volatile("s_waitcnt vmcnt(0)" ::: "memory");   // drain A_127,B_127
    BAR();
    read_set<1>(aO0, bO0, aK0, aK0_2, bK0, bK0_2);
    LGKM(12);                                          // S(126,0) ready
    mfma_tile(acc, aE0, bE0);
    read_set<1>(aO1, bO1, aK1, aK1_2, bK1, bK1_2);
    LGKM(12);                                          // S(126,1) ready
    mfma_tile(acc, aE1, bE1);
    LGKM(6);                                           // S(127,0) ready
    mfma_tile(acc, aO0, bO0);
    LGKM(0);                                           // S(127,1) ready
    mfma_tile(acc, aO1, bO1);

    // ---- epilogue: 32x32 C/D layout col=lane&31,
    // row = (reg&3) + 8*(reg>>2) + 4*(lane>>5) ----
    int orow0 = brow + wr * 128 + 4 * hi;
    int ocol0 = bcol + wc * 64 + l31;
#pragma unroll
    for (int n = 0; n < 2; ++n) {
        int col = ocol0 + n * 32;
        float bval = bias[col];
#pragma unroll
        for (int m = 0; m < 4; ++m) {
            int rbase = orow0 + m * 32;
#pragma unroll
            for (int j = 0; j < 16; ++j) {
                int row = rbase + (j & 3) + 8 * (j >> 2);
                C[(int64_t)row * N_DIM + col] = acc[m][n][j] + bval;
            }
        }
    }
}

extern "C" void kernel_launch(void* const* d_in, const int* in_sizes, int n_in,
                              void* d_out, int out_size, void* d_ws, size_t ws_size,
                              hipStream_t stream) {
    const float* x      = (const float*)d_in[0];
    const int* ci       = (const int*)d_in[1];
    const int* wp       = (const int*)d_in[2];
    const float* scales = (const float*)d_in[3];
    const float* bias   = (const float*)d_in[4];
    float* out          = (float*)d_out;

    const size_t wT_bytes = (size_t)N_DIM * K_DIM * 2;
    unsigned short* wT = (unsigned short*)d_ws;
    unsigned short* xg = wT + (size_t)N_DIM * K_DIM;

    size_t cap = (ws_size > wT_bytes) ? (ws_size - wT_bytes) : 0;
    int max_rows = (int)(cap / ((size_t)K_DIM * 2));
    int chunk_rows = (max_rows / 256) * 256;
    if (chunk_rows <= 0) chunk_rows = 256;      // best effort
    if (chunk_rows > M_DIM) chunk_rows = M_DIM;

    dequant_w_kernel<<<dim3(N_DIM / 64, K_DIM / 64), 256, 0, stream>>>(wp, scales, wT);

    for (int m0 = 0; m0 < M_DIM; m0 += chunk_rows) {
        int rows = M_DIM - m0 < chunk_rows ? M_DIM - m0 : chunk_rows;
        int pgrid = (int)(((int64_t)rows * K_DIM) / (4 * 256));
        permute_x_kernel<<<pgrid, 256, 0, stream>>>(
            x + (int64_t)m0 * K_DIM, ci, xg);
        int grid = (rows / 256) * (N_DIM / 256);
        gemm_kernel<<<grid, 512, 0, stream>>>(
            xg, wT, bias, out + (int64_t)m0 * N_DIM);
    }
}

// Round 13
// 813.682 us; speedup vs baseline: 1.3257x; 1.0787x over previous
//
#include <hip/hip_runtime.h>
#include <hip/hip_bf16.h>
#include <stdint.h>

#define M_DIM 8192
#define K_DIM 4096
#define N_DIM 11008

typedef __attribute__((ext_vector_type(8))) short bf16x8;
typedef __attribute__((ext_vector_type(4))) float f32x4;
typedef __attribute__((ext_vector_type(4))) unsigned int uint4v;

__device__ __forceinline__ unsigned short f2bf(float f) {
    __hip_bfloat16 h = __float2bfloat16(f);
    return __builtin_bit_cast(unsigned short, h);
}

__device__ __forceinline__ void gload_lds16(const unsigned short* g, unsigned short* l) {
    __builtin_amdgcn_global_load_lds(
        (const __attribute__((address_space(1))) void*)g,
        (__attribute__((address_space(3))) void*)l,
        16, 0, 0);
}

__device__ __forceinline__ unsigned lds_addr(const unsigned short* p) {
    return (unsigned)(uintptr_t)(const __attribute__((address_space(3))) unsigned short*)p;
}

// inline-asm ds_read_b128 with immediate offset; hand-placed counted lgkm
// waits order the consumers.
#define DSRI(dst, a, OFF) asm volatile("ds_read_b128 %0, %1 offset:%2" \
    : "=v"(dst) : "v"(a), "n"(OFF) : "memory")

// counted lgkm wait + scheduler fence (rule #18).
#define LGKM(N) do { \
    asm volatile("s_waitcnt lgkmcnt(" #N ")" ::: "memory"); \
    __builtin_amdgcn_sched_barrier(0); \
} while (0)
#define VMC(N) asm volatile("s_waitcnt vmcnt(" #N ")" ::: "memory")
#define BAR() do { __builtin_amdgcn_s_barrier(); asm volatile("" ::: "memory"); } while (0)

// ---------------------------------------------------------------------------
// Kernel 1: fused column-gather + fp32->bf16 convert.
// ---------------------------------------------------------------------------
__global__ void permute_x_kernel(const float* __restrict__ x,
                                 const int* __restrict__ ci,
                                 unsigned short* __restrict__ xg) {
    int idx = blockIdx.x * 256 + threadIdx.x;
    int64_t base = (int64_t)idx * 4;
    int m = (int)(base >> 12);        // K=4096
    int k = (int)(base & 4095);
    const float* xrow = x + ((int64_t)m << 12);
    int4 c4 = *reinterpret_cast<const int4*>(ci + k);
    ushort4 o;
    o.x = f2bf(xrow[c4.x]);
    o.y = f2bf(xrow[c4.y]);
    o.z = f2bf(xrow[c4.z]);
    o.w = f2bf(xrow[c4.w]);
    *reinterpret_cast<ushort4*>(xg + base) = o;
}

// ---------------------------------------------------------------------------
// Kernel 2: int4 unpack + per-group scale + transpose to wT[N][K] bf16.
// ---------------------------------------------------------------------------
__global__ void dequant_w_kernel(const int* __restrict__ wp,
                                 const float* __restrict__ scales,
                                 unsigned short* __restrict__ wT) {
    __shared__ unsigned short tile[64][65];
    int n0 = blockIdx.x * 64;
    int k0 = blockIdx.y * 64;
    int g = k0 >> 7;
    int t = threadIdx.x;
    int col = t & 63;
    int r0 = t >> 6;
    float s = scales[(int64_t)g * N_DIM + n0 + col];
    int pr0 = k0 >> 1;
#pragma unroll
    for (int i = 0; i < 8; ++i) {
        int row = r0 + i * 4;
        int p = wp[(int64_t)(pr0 + row) * N_DIM + n0 + col];
        tile[2 * row][col]     = f2bf((float)((p & 15) - 8) * s);
        tile[2 * row + 1][col] = f2bf((float)(((p >> 4) & 15) - 8) * s);
    }
    __syncthreads();
    int nl = t >> 2;
    int kk0 = (t & 3) << 4;
    unsigned short vals[16];
#pragma unroll
    for (int j = 0; j < 16; ++j) vals[j] = tile[kk0 + j][nl];
    uint4v* dst = reinterpret_cast<uint4v*>(wT + (int64_t)(n0 + nl) * K_DIM + k0 + kk0);
    dst[0] = *reinterpret_cast<const uint4v*>(&vals[0]);
    dst[1] = *reinterpret_cast<const uint4v*>(&vals[8]);
}

// ---------------------------------------------------------------------------
// Kernel 3: bf16 GEMM = round-7 kernel (best family: 256x256, BK=32,
// 16x16x32 MFMA, 2 barriers/tile, 0 bank conflicts) with TWO changes:
//  (a) 4-BUFFER rotation (128 KiB LDS): stage tile j+3 (was j+2), vmcnt(6)
//      (was 2). Stage->confirm headroom 1.3 -> 2.3 phases (~2900 cyc),
//      matching m201's 3-half-tile-in-flight depth. Occupancy unchanged
//      (1 block/CU either way).
//  (b) s_setprio REMOVED (m190: slightly negative on lockstep GEMM).
//
// Per K-tile j (buf B=j%4, BN=(j+1)%4, BS=(j+3)%4): 2 phases.
//  P1: issue RB_j (4 ds: A m4-7); stage A_{j+3}->BS; LGKM(4) [drains RA_j];
//      16 MFMA (m0-3); vmcnt(6); BAR.
//  P2: issue RA_{j+1} (8 ds: A m0-3 + B n0-3 of buf BN); stage B_{j+3};
//      LGKM(8) [drains RB_j]; 16 MFMA (m4-7); BAR.
//
// vmcnt ledger (2 gloads per stage region): at P1(j) after issuing A_{j+3},
// outstanding = {A_{j+1},B_{j+1},A_{j+2},B_{j+2},A_{j+3}} = 10 -> vmcnt(6)
// drains A_{j+1},B_{j+1}: buf j+1 confirmed by every wave BEFORE the BAR,
// and RA_{j+1} is issued AFTER that BAR (r10 lesson: no stale reads).
// Overwrite ledger: stage A_{j+3} writes buf (j+3)%4 == (j-1)%4; its last
// reads (RB_{j-1}) drained at P2(j-1)'s LGKM(8), >=1 barrier (P2 end-BAR)
// before the stage issue at P1(j). Safe for all waves.
// Prologue stages tiles 0,1,2 (12 gloads); vmcnt(8) confirms tile 0; loop
// enters with {A1,B1,A2,B2}=8 outstanding = steady state. Tail: tile 124
// stages tile 127 (normal macro); tiles 125/126/127 stage nothing with
// vmcnt 4 / 0 / none.
//
// Swizzle (r5, measured 0 conflicts on this fragment map):
// phys = lin ^ ((fr&6)<<3), fr=lane&15; staging source col perm
// s8 = ((lane&3)^((lane>>3)&3))<<3.
// ---------------------------------------------------------------------------

template <int BUF>
__device__ __forceinline__ void read_RA(bf16x8 (&a)[4], bf16x8 (&b)[4],
                                        unsigned aA01, unsigned aA23,
                                        unsigned bB01, unsigned bB23) {
    const unsigned ad = (BUF < 2) ? aA01 : aA23;
    const unsigned bd = (BUF < 2) ? bB01 : bB23;
    constexpr int bo = (BUF & 1) * 32768;
    DSRI(a[0], ad, bo + 0);
    DSRI(a[1], ad, bo + 1024);
    DSRI(a[2], ad, bo + 2048);
    DSRI(a[3], ad, bo + 3072);
    DSRI(b[0], bd, bo + 0);
    DSRI(b[1], bd, bo + 1024);
    DSRI(b[2], bd, bo + 2048);
    DSRI(b[3], bd, bo + 3072);
}

template <int BUF>
__device__ __forceinline__ void read_RB(bf16x8 (&a2)[4], unsigned aA01, unsigned aA23) {
    const unsigned ad = (BUF < 2) ? aA01 : aA23;
    constexpr int bo = (BUF & 1) * 32768;
    DSRI(a2[0], ad, bo + 4096);
    DSRI(a2[1], ad, bo + 5120);
    DSRI(a2[2], ad, bo + 6144);
    DSRI(a2[3], ad, bo + 7168);
}

template <int MB>
__device__ __forceinline__ void mfma4(f32x4 (&acc)[8][4], const bf16x8 (&av)[4],
                                      const bf16x8 (&bv)[4]) {
#pragma unroll
    for (int m = 0; m < 4; ++m)
#pragma unroll
        for (int n = 0; n < 4; ++n)
            acc[MB + m][n] = __builtin_amdgcn_mfma_f32_16x16x32_bf16(
                av[m], bv[n], acc[MB + m][n], 0, 0, 0);
}

// stage one 16 KiB region (256 rows x 32 k) of K-tile t into buf DBUF.
template <int DBUF, int ISB>
__device__ __forceinline__ void stage2(const unsigned short* p0, const unsigned short* p1,
                                       int t, unsigned short* lds, int wLds) {
    const unsigned short* s0 = p0 + t * 32;
    const unsigned short* s1 = p1 + t * 32;
    unsigned short* d = lds + DBUF * 16384 + ISB * 8192 + wLds;
    gload_lds16(s0, d);
    gload_lds16(s1, d + 512);
}

// one K-tile: B=buf j%4, BN=(j+1)%4, BS=(j+3)%4; CA_/CB_ = consume color
// frags (tile j), NA_/NB_ = next color frags (tile j+1); tt = j+3.
#define PH_TILE(B, BN, BS, CA_, CB_, NA_, NB_, tt)                        \
    do {                                                                  \
        read_RB<B>(a2, aA01, aA23);                                       \
        stage2<BS, 0>(pA0, pA1, (tt), lds, wLds);                         \
        LGKM(4);                                                          \
        mfma4<0>(acc, CA_, CB_);                                          \
        VMC(6);                                                           \
        BAR();                                                            \
        read_RA<BN>(NA_, NB_, aA01, aA23, bB01, bB23);                    \
        stage2<BS, 1>(pB0, pB1, (tt), lds, wLds);                         \
        LGKM(8);                                                          \
        mfma4<4>(acc, a2, CB_);                                           \
        BAR();                                                            \
    } while (0)

__global__ __launch_bounds__(512, 2)
void gemm_kernel(const unsigned short* __restrict__ A,
                 const unsigned short* __restrict__ BT,
                 const float* __restrict__ bias,
                 float* __restrict__ C) {
    __shared__ unsigned short lds[65536];   // 128 KiB: 4 bufs x 32 KiB

    constexpr int NT = N_DIM / 256;  // 43
    int wg = blockIdx.x, nwg = gridDim.x;
    int q = nwg >> 3, r = nwg & 7;
    int xcd = wg & 7, li = wg >> 3;
    int swz = (xcd < r ? xcd * (q + 1) : r * (q + 1) + (xcd - r) * q) + li;
    int by = swz / NT, bx = swz - by * NT;
    int brow = by << 8, bcol = bx << 8;

    int t = threadIdx.x;
    int lane = t & 63, w = t >> 6;
    int wr = w >> 2, wc = w & 3;           // 2 x 4 wave grid
    int fr = lane & 15, fq = lane >> 4;

    // T2 bank swizzle (r5, measured 0 conflicts): read XOR on byte bits 4-5;
    // inverse source col perm on staging.
    const unsigned xr = (unsigned)((fr & 6) << 3);
    const int riw = lane >> 2;
    const int s8 = ((lane & 3) ^ ((lane >> 3) & 3)) << 3;
    const int w32 = w * 32, wLds = w * 1024;

    const unsigned ldsB = lds_addr(lds);
    const unsigned aA01 = ldsB + ((unsigned)((wr * 128 + fr) * 64 + fq * 16) ^ xr);
    const unsigned bB01 = ldsB + 16384u + ((unsigned)((wc * 64 + fr) * 64 + fq * 16) ^ xr);
    const unsigned aA23 = aA01 + 65536;
    const unsigned bB23 = bB01 + 65536;

    // staging source pointers (row slice fixed per thread; k via t*32)
    const unsigned short* pA0 = A + (int64_t)(brow + w32 + riw) * K_DIM + s8;
    const unsigned short* pA1 = pA0 + 16 * K_DIM;
    const unsigned short* pB0 = BT + (int64_t)(bcol + w32 + riw) * K_DIM + s8;
    const unsigned short* pB1 = pB0 + 16 * K_DIM;

    f32x4 acc[8][4];
#pragma unroll
    for (int m = 0; m < 8; ++m)
#pragma unroll
        for (int n = 0; n < 4; ++n) acc[m][n] = (f32x4){0.f, 0.f, 0.f, 0.f};

    bf16x8 aX[4], bX[4], aY[4], bY[4], a2[4];

    // ---- prologue: stage tiles 0,1,2 -> bufs 0,1,2 (12 gloads); vmcnt(8)
    // confirms tile 0 (leaves {A1,B1,A2,B2}=8 = steady state); pre-issue
    // RA_0 (color X).
    stage2<0, 0>(pA0, pA1, 0, lds, wLds);
    stage2<0, 1>(pB0, pB1, 0, lds, wLds);
    stage2<1, 0>(pA0, pA1, 1, lds, wLds);
    stage2<1, 1>(pB0, pB1, 1, lds, wLds);
    stage2<2, 0>(pA0, pA1, 2, lds, wLds);
    stage2<2, 1>(pB0, pB1, 2, lds, wLds);
    VMC(8);
    BAR();
    read_RA<0>(aX, bX, aA01, aA23, bB01, bB23);

    // main loop: 31 bodies x 4 tiles = tiles 0..123 (stages reach tile 126).
#pragma unroll 1
    for (int body = 0; body < 31; ++body) {
        const int t3 = body * 4 + 3;
        PH_TILE(0, 1, 3, aX, bX, aY, bY, t3);       // tile 4b+0 (X -> Y)
        PH_TILE(1, 2, 0, aY, bY, aX, bX, t3 + 1);   // tile 4b+1 (Y -> X)
        PH_TILE(2, 3, 1, aX, bX, aY, bY, t3 + 2);   // tile 4b+2 (X -> Y)
        PH_TILE(3, 0, 2, aY, bY, aX, bX, t3 + 3);   // tile 4b+3 (Y -> X)
    }

    // ---- tail ----
    // tile 124 (buf 0, X): normal macro, stages tile 127 into buf 3.
    PH_TILE(0, 1, 3, aX, bX, aY, bY, 127);
    // tile 125 (buf 1, Y): no stage; vmcnt(4) confirms buf 126.
    read_RB<1>(a2, aA01, aA23);
    LGKM(4);
    mfma4<0>(acc, aY, bY);
    VMC(4);
    BAR();
    read_RA<2>(aX, bX, aA01, aA23, bB01, bB23);
    LGKM(8);
    mfma4<4>(acc, a2, bY);
    BAR();
    // tile 126 (buf 2, X): no stage; vmcnt(0) confirms buf 127.
    read_RB<2>(a2, aA01, aA23);
    LGKM(4);
    mfma4<0>(acc, aX, bX);
    VMC(0);
    BAR();
    read_RA<3>(aY, bY, aA01, aA23, bB01, bB23);
    LGKM(8);
    mfma4<4>(acc, a2, bX);
    BAR();
    // tile 127 (buf 3, Y): final.
    read_RB<3>(a2, aA01, aA23);
    LGKM(4);
    mfma4<0>(acc, aY, bY);
    LGKM(0);
    mfma4<4>(acc, a2, bY);

    // ---- epilogue: 16x16 C/D layout col=lane&15, row=(lane>>4)*4+reg ----
    int orow0 = brow + wr * 128 + fq * 4;
    int ocol0 = bcol + wc * 64 + fr;
#pragma unroll
    for (int n = 0; n < 4; ++n) {
        int col = ocol0 + n * 16;
        float bval = bias[col];
#pragma unroll
        for (int m = 0; m < 8; ++m) {
            int row = orow0 + m * 16;
            float* cp = C + (int64_t)row * N_DIM + col;
#pragma unroll
            for (int j = 0; j < 4; ++j) {
                cp[(int64_t)j * N_DIM] = acc[m][n][j] + bval;
            }
        }
    }
}

extern "C" void kernel_launch(void* const* d_in, const int* in_sizes, int n_in,
                              void* d_out, int out_size, void* d_ws, size_t ws_size,
                              hipStream_t stream) {
    const float* x      = (const float*)d_in[0];
    const int* ci       = (const int*)d_in[1];
    const int* wp       = (const int*)d_in[2];
    const float* scales = (const float*)d_in[3];
    const float* bias   = (const float*)d_in[4];
    float* out          = (float*)d_out;

    const size_t wT_bytes = (size_t)N_DIM * K_DIM * 2;
    unsigned short* wT = (unsigned short*)d_ws;
    unsigned short* xg = wT + (size_t)N_DIM * K_DIM;

    size_t cap = (ws_size > wT_bytes) ? (ws_size - wT_bytes) : 0;
    int max_rows = (int)(cap / ((size_t)K_DIM * 2));
    int chunk_rows = (max_rows / 256) * 256;
    if (chunk_rows <= 0) chunk_rows = 256;      // best effort
    if (chunk_rows > M_DIM) chunk_rows = M_DIM;

    dequant_w_kernel<<<dim3(N_DIM / 64, K_DIM / 64), 256, 0, stream>>>(wp, scales, wT);

    for (int m0 = 0; m0 < M_DIM; m0 += chunk_rows) {
        int rows = M_DIM - m0 < chunk_rows ? M_DIM - m0 : chunk_rows;
        int pgrid = (int)(((int64_t)rows * K_DIM) / (4 * 256));
        permute_x_kernel<<<pgrid, 256, 0, stream>>>(
            x + (int64_t)m0 * K_DIM, ci, xg);
        int grid = (rows / 256) * (N_DIM / 256);
        gemm_kernel<<<grid, 512, 0, stream>>>(
            xg, wT, bias, out + (int64_t)m0 * N_DIM);
    }
}